// Round 1
// baseline (799.316 us; speedup 1.0000x reference)
//
#include <hip/hip_runtime.h>

#define BATCH 4
#define HH 256
#define WW 256
#define HT 513   // convT output spatial
#define HO 511   // final output spatial

typedef __attribute__((ext_vector_type(8))) short bf16x8;
typedef __attribute__((ext_vector_type(4))) float f32x4;

// ---------- bf16 helpers ----------
__device__ __forceinline__ unsigned short f2bf(float f) {
    unsigned b = __float_as_uint(f);
    unsigned r = (b + 0x7fffu + ((b >> 16) & 1u)) >> 16;  // RNE
    return (unsigned short)r;
}

// ---------- 0: zero mask0 + x (contiguous region) ----------
__global__ void k_zero(float* __restrict__ p, int n4) {
    int i = blockIdx.x * blockDim.x + threadIdx.x;
    if (i < n4) ((float4*)p)[i] = make_float4(0.f, 0.f, 0.f, 0.f);
}

// ---------- 1: scatter-add features (fp32), set occupancy ----------
__global__ void k_scatter(const float* __restrict__ feat,
                          const int* __restrict__ coors,
                          float* __restrict__ x, float* __restrict__ mask0, int N) {
    int t = blockIdx.x * blockDim.x + threadIdx.x;
    int n = t >> 5, c = t & 31;
    if (n >= N) return;
    int b  = coors[n * 3 + 0];
    int y  = coors[n * 3 + 1];
    int xx = coors[n * 3 + 2];
    float f = feat[n * 32 + c];
    int pix = (b * HH + y) * WW + xx;
    atomicAdd(&x[pix * 32 + c], f);
    if (c == 0) mask0[pix] = 1.0f;
}

// ---------- 2: 3x3 dilate mask (SAME) ----------
__global__ void k_mask1(const float* __restrict__ mask0, float* __restrict__ mask1, int total) {
    int t = blockIdx.x * blockDim.x + threadIdx.x;
    if (t >= total) return;
    int xx = t % WW;
    int y  = (t / WW) % HH;
    int b  = t / (WW * HH);
    float m = 0.f;
    #pragma unroll
    for (int dy = -1; dy <= 1; ++dy) {
        int iy = y + dy;
        if ((unsigned)iy >= HH) continue;
        #pragma unroll
        for (int dx = -1; dx <= 1; ++dx) {
            int ix = xx + dx;
            if ((unsigned)ix >= WW) continue;
            m = fmaxf(m, mask0[(b * HH + iy) * WW + ix]);
        }
    }
    mask1[t] = (m > 0.f) ? 1.f : 0.f;
}

// ---------- 2b: transpose-dilate mask: mask4[B][513][513] ----------
__global__ void k_mask4(const float* __restrict__ mask1, float* __restrict__ mask4, int total) {
    int t = blockIdx.x * blockDim.x + threadIdx.x;
    if (t >= total) return;
    int ox = t % HT;
    int oy = (t / HT) % HT;
    int b  = t / (HT * HT);
    float m = 0.f;
    #pragma unroll
    for (int ky = 0; ky < 3; ++ky) {
        int q = oy + ky - 2;
        if ((q & 1) || (unsigned)(q >> 1) >= (unsigned)HH) continue;
        int iy = q >> 1;
        #pragma unroll
        for (int kx = 0; kx < 3; ++kx) {
            int r = ox + kx - 2;
            if ((r & 1) || (unsigned)(r >> 1) >= (unsigned)WW) continue;
            m = fmaxf(m, mask1[(b * HH + iy) * WW + (r >> 1)]);
        }
    }
    mask4[t] = (m > 0.f) ? 1.f : 0.f;
}

// ---------- 2c: cast x fp32 -> bf16 (8 elems/thread) ----------
__global__ void k_cast(const float* __restrict__ src, unsigned short* __restrict__ dst, int n8) {
    int i = blockIdx.x * blockDim.x + threadIdx.x;
    if (i >= n8) return;
    float4 a = ((const float4*)src)[2 * i];
    float4 c = ((const float4*)src)[2 * i + 1];
    uint4 o;
    o.x = (unsigned)f2bf(a.x) | ((unsigned)f2bf(a.y) << 16);
    o.y = (unsigned)f2bf(a.z) | ((unsigned)f2bf(a.w) << 16);
    o.z = (unsigned)f2bf(c.x) | ((unsigned)f2bf(c.y) << 16);
    o.w = (unsigned)f2bf(c.z) | ((unsigned)f2bf(c.w) << 16);
    ((uint4*)dst)[i] = o;
}

// ---------- 2d: pack weights [K][64] fp32 -> MFMA B-fragment order ----------
// dst[t][nb][lane][j] (bf16) = w[k][n], k = t*32 + (lane>>4)*8 + j, n = nb*16 + (lane&15)
__global__ void k_pack(const float* __restrict__ w, unsigned short* __restrict__ dst, int T) {
    int t = blockIdx.x * blockDim.x + threadIdx.x;
    if (t >= T * 256) return;
    int step = t >> 8;
    int r = t & 255;
    int nb = r >> 6;
    int l = r & 63;
    int k = step * 32 + ((l >> 4) * 8);
    int n = nb * 16 + (l & 15);
    unsigned short tmp[8];
    #pragma unroll
    for (int j = 0; j < 8; ++j) tmp[j] = f2bf(w[(size_t)(k + j) * 64 + n]);
    uint4 o;
    o.x = (unsigned)tmp[0] | ((unsigned)tmp[1] << 16);
    o.y = (unsigned)tmp[2] | ((unsigned)tmp[3] << 16);
    o.z = (unsigned)tmp[4] | ((unsigned)tmp[5] << 16);
    o.w = (unsigned)tmp[6] | ((unsigned)tmp[7] << 16);
    *(uint4*)(dst + (size_t)((step * 4 + nb) * 64 + l) * 8) = o;
}

// ---------- MFMA conv: wave = 64 px x 64 cout ----------
// B fragments loaded per-wave straight from global (73 KB, L2-hot): no LDS,
// no __syncthreads -> waves fully independent, compiler pipelines freely.
// Bijective XCD-chunk swizzle (T1/m204) so adjacent output rows share an XCD L2.
enum Mode { CONV, CONVT2 };

template <int CIN, int IN_H, int IN_W, int OUT_H, int OUT_W, int PAD,
          Mode MODE, bool MASKED, bool OUT_F32>
__global__ __launch_bounds__(256) void k_conv_mfma(
    const unsigned short* __restrict__ in,   // bf16 [B][IN_H][IN_W][CIN]
    const unsigned short* __restrict__ bp,   // packed B frags [T][4][64][8], T=9*CIN/32
    const float* __restrict__ bias,          // [64]
    const float* __restrict__ mask,          // [B][OUT_H][OUT_W] (if MASKED)
    void* __restrict__ outv)                 // bf16 or fp32 [B][OUT_H][OUT_W][64]
{
    constexpr int H2 = CIN / 32;                 // K-steps per tap
    constexpr int XT = (OUT_W + 255) / 256;      // 256 px per block

    // --- XCD-aware bijective swizzle: each XCD gets a contiguous chunk ---
    int nwg  = (int)gridDim.x;
    int orig = (int)blockIdx.x;
    int q8 = nwg >> 3, r8 = nwg & 7;
    int xcd = orig & 7, pos = orig >> 3;
    int blk = (xcd < r8 ? xcd * (q8 + 1) : r8 * (q8 + 1) + (xcd - r8) * q8) + pos;

    int s = blk % XT;
    int y = (blk / XT) % OUT_H;
    int b = blk / (XT * OUT_H);
    int tid  = threadIdx.x;
    int lane = tid & 63;
    int wid  = tid >> 6;
    int m    = lane & 15;
    int quad = lane >> 4;

    int px_base, par;
    if constexpr (MODE == CONV) { px_base = s * 256 + wid * 64; par = 0; }
    else { par = wid & 1; px_base = s * 256 + (wid >> 1) * 128; }

    const uint4* bp4 = (const uint4*)bp;         // [T][4][64] uint4s

    f32x4 acc[4][4] = {};

    #pragma unroll
    for (int ky = 0; ky < 3; ++ky) {
        int iy; bool rowv;
        if constexpr (MODE == CONV) {
            iy = y + ky - PAD;
            rowv = (unsigned)iy < (unsigned)IN_H;
        } else {
            int q = y + ky - 2;
            rowv = (!(q & 1)) && ((unsigned)(q >> 1) < (unsigned)IN_H);
            iy = q >> 1;
        }
        if (!rowv) continue;                      // block-uniform (y, ky uniform)

        const unsigned short* inrow = in + (size_t)(b * IN_H + iy) * IN_W * CIN;

        #pragma unroll
        for (int kx = 0; kx < 3; ++kx) {
            if constexpr (MODE == CONVT2) {
                if ((kx & 1) != par) continue;    // wave-uniform parity skip
            }
            int ix[4]; bool v[4];
            #pragma unroll
            for (int f = 0; f < 4; ++f) {
                if constexpr (MODE == CONV) {
                    int ox = px_base + f * 16 + m;
                    int t = ox + kx - PAD;
                    v[f]  = (ox < OUT_W) & ((unsigned)t < (unsigned)IN_W);
                    ix[f] = min(max(t, 0), IN_W - 1);
                } else {
                    int ox = px_base + 2 * (f * 16 + m) + par;
                    int r = ox + kx - 2;          // even by construction
                    int t = r >> 1;
                    v[f]  = (ox < OUT_W) & ((unsigned)t < (unsigned)IN_W);
                    ix[f] = min(max(t, 0), IN_W - 1);
                }
            }
            #pragma unroll
            for (int half = 0; half < H2; ++half) {
                int t = (ky * 3 + kx) * H2 + half;       // global K-step index
                const uint4* bsrc = bp4 + (size_t)t * 256 + lane;
                bf16x8 bfr[4];
                #pragma unroll
                for (int nb = 0; nb < 4; ++nb)
                    bfr[nb] = __builtin_bit_cast(bf16x8, bsrc[nb * 64]);
                #pragma unroll
                for (int f = 0; f < 4; ++f) {
                    const unsigned short* ap =
                        inrow + (size_t)ix[f] * CIN + half * 32 + quad * 8;
                    uint4 av = v[f] ? *(const uint4*)ap : make_uint4(0u, 0u, 0u, 0u);
                    bf16x8 a = __builtin_bit_cast(bf16x8, av);
                    #pragma unroll
                    for (int nb = 0; nb < 4; ++nb)
                        acc[f][nb] = __builtin_amdgcn_mfma_f32_16x16x32_bf16(
                            a, bfr[nb], acc[f][nb], 0, 0, 0);
                }
            }
        }
    }

    // epilogue: C/D layout col = lane&15 (cout in nb), row = quad*4+reg (pixel in frag)
    int n0 = m;
    float bv[4];
    #pragma unroll
    for (int nb = 0; nb < 4; ++nb) bv[nb] = bias[nb * 16 + n0];
    #pragma unroll
    for (int f = 0; f < 4; ++f) {
        #pragma unroll
        for (int reg = 0; reg < 4; ++reg) {
            int i = f * 16 + quad * 4 + reg;
            int pm;
            if constexpr (MODE == CONV) pm = px_base + i;
            else pm = px_base + 2 * i + par;
            if (pm >= OUT_W) continue;
            size_t pix = (size_t)(b * OUT_H + y) * OUT_W + pm;
            float mk = 1.f;
            if constexpr (MASKED) mk = mask[pix];
            #pragma unroll
            for (int nb = 0; nb < 4; ++nb) {
                float o = fmaxf((acc[f][nb][reg] + bv[nb]) * mk, 0.f);
                if constexpr (OUT_F32)
                    ((float*)outv)[pix * 64 + nb * 16 + n0] = o;
                else
                    ((unsigned short*)outv)[pix * 64 + nb * 16 + n0] = f2bf(o);
            }
        }
    }
}

// ---------- host ----------
extern "C" void kernel_launch(void* const* d_in, const int* in_sizes, int n_in,
                              void* d_out, int out_size, void* d_ws, size_t ws_size,
                              hipStream_t stream) {
    const float* feat = (const float*)d_in[0];
    const int* coors  = (const int*)d_in[1];
    const float* w1 = (const float*)d_in[3];
    const float* b1 = (const float*)d_in[4];
    const float* w2 = (const float*)d_in[5];
    const float* b2 = (const float*)d_in[6];
    const float* w3 = (const float*)d_in[7];
    const float* b3 = (const float*)d_in[8];
    const float* wt = (const float*)d_in[9];
    const float* bt = (const float*)d_in[10];
    const float* w5 = (const float*)d_in[11];
    const float* b5 = (const float*)d_in[12];

    int N = in_sizes[0] / 32;  // 200000

    const size_t MB = 1024 * 1024;
    char* ws = (char*)d_ws;
    // layout (liveness-based reuse), total 177 MB:
    unsigned short* pk1 = (unsigned short*)(ws);             // 36,864 B
    unsigned short* pk2 = (unsigned short*)(ws + 36864);     // 73,728 B
    unsigned short* pk3 = (unsigned short*)(ws + 110592);
    unsigned short* pkt = (unsigned short*)(ws + 184320);
    unsigned short* pk5 = (unsigned short*)(ws + 258048);    // ends 331,776
    float* mask1 = (float*)(ws + 1 * MB);                    // 1 MB
    float* mask4 = (float*)(ws + 2 * MB);                    // 4.02 MB
    float* mask0 = (float*)(ws + 7 * MB);                    // 1 MB   (contiguous with x)
    float* x_f32 = (float*)(ws + 8 * MB);                    // 33.55 MB
    unsigned short* x_bf  = (unsigned short*)(ws + 42 * MB); // 16.78 MB
    unsigned short* h1    = (unsigned short*)(ws + 59 * MB); // 33.55 MB
    unsigned short* h2    = (unsigned short*)(ws + 93 * MB); // 33.55 MB
    unsigned short* h3    = (unsigned short*)(ws + 8 * MB);  // reuses x_f32 (dead after cast)
    unsigned short* h4    = (unsigned short*)(ws + 42 * MB); // 134.75 MB, reuses x_bf/h1/h2

    // 0: zero mask0 + x (contiguous 34,603,008 B)
    int nz4 = (262144 + 8388608) / 4;
    k_zero<<<(nz4 + 255) / 256, 256, 0, stream>>>(mask0, nz4);

    // 1: scatter (fp32 atomics)
    k_scatter<<<(N * 32 + 255) / 256, 256, 0, stream>>>(feat, coors, x_f32, mask0, N);

    // 2: masks + cast + weight packing
    k_mask1<<<(BATCH * HH * WW) / 256, 256, 0, stream>>>(mask0, mask1, BATCH * HH * WW);
    int m4tot = BATCH * HT * HT;
    k_mask4<<<(m4tot + 255) / 256, 256, 0, stream>>>(mask1, mask4, m4tot);
    k_cast<<<(1048576 + 255) / 256, 256, 0, stream>>>(x_f32, x_bf, 1048576);
    k_pack<<<9, 256, 0, stream>>>(w1, pk1, 9);
    k_pack<<<18, 256, 0, stream>>>(w2, pk2, 18);
    k_pack<<<18, 256, 0, stream>>>(w3, pk3, 18);
    k_pack<<<18, 256, 0, stream>>>(wt, pkt, 18);
    k_pack<<<18, 256, 0, stream>>>(w5, pk5, 18);

    // 3-5: conv stack at 256x256 (bf16 MFMA, 256 px/block)
    k_conv_mfma<32, 256, 256, 256, 256, 1, CONV, true, false>
        <<<BATCH * HH * 1, 256, 0, stream>>>(x_bf, pk1, b1, mask1, h1);
    k_conv_mfma<64, 256, 256, 256, 256, 1, CONV, true, false>
        <<<BATCH * HH * 1, 256, 0, stream>>>(h1, pk2, b2, mask1, h2);
    k_conv_mfma<64, 256, 256, 256, 256, 1, CONV, true, false>
        <<<BATCH * HH * 1, 256, 0, stream>>>(h2, pk3, b3, mask1, h3);

    // 6: transpose conv 256 -> 513 (parity-specialized waves)
    k_conv_mfma<64, 256, 256, HT, HT, 0, CONVT2, true, false>
        <<<BATCH * HT * 3, 256, 0, stream>>>(h3, pkt, bt, mask4, h4);

    // 7: final VALID conv 513 -> 511 into d_out (fp32)
    k_conv_mfma<64, HT, HT, HO, HO, 0, CONV, false, true>
        <<<BATCH * HO * 2, 256, 0, stream>>>(h4, pk5, b5, nullptr, (float*)d_out);
}

// Round 2
// 714.926 us; speedup vs baseline: 1.1180x; 1.1180x over previous
//
#include <hip/hip_runtime.h>

#define BATCH 4
#define HH 256
#define WW 256
#define HT 513   // convT output spatial
#define HO 511   // final output spatial

typedef __attribute__((ext_vector_type(8))) short bf16x8;
typedef __attribute__((ext_vector_type(4))) float f32x4;

// ---------- bf16 helpers ----------
__device__ __forceinline__ unsigned short f2bf(float f) {
    unsigned b = __float_as_uint(f);
    unsigned r = (b + 0x7fffu + ((b >> 16) & 1u)) >> 16;  // RNE
    return (unsigned short)r;
}

// ---------- 0: zero mask0 + x (contiguous region) ----------
__global__ void k_zero(float* __restrict__ p, int n4) {
    int i = blockIdx.x * blockDim.x + threadIdx.x;
    if (i < n4) ((float4*)p)[i] = make_float4(0.f, 0.f, 0.f, 0.f);
}

// ---------- 1: scatter-add features (fp32), set occupancy ----------
__global__ void k_scatter(const float* __restrict__ feat,
                          const int* __restrict__ coors,
                          float* __restrict__ x, float* __restrict__ mask0, int N) {
    int t = blockIdx.x * blockDim.x + threadIdx.x;
    int n = t >> 5, c = t & 31;
    if (n >= N) return;
    int b  = coors[n * 3 + 0];
    int y  = coors[n * 3 + 1];
    int xx = coors[n * 3 + 2];
    float f = feat[n * 32 + c];
    int pix = (b * HH + y) * WW + xx;
    atomicAdd(&x[pix * 32 + c], f);
    if (c == 0) mask0[pix] = 1.0f;
}

// ---------- 2: 3x3 dilate mask (SAME) ----------
__global__ void k_mask1(const float* __restrict__ mask0, float* __restrict__ mask1, int total) {
    int t = blockIdx.x * blockDim.x + threadIdx.x;
    if (t >= total) return;
    int xx = t % WW;
    int y  = (t / WW) % HH;
    int b  = t / (WW * HH);
    float m = 0.f;
    #pragma unroll
    for (int dy = -1; dy <= 1; ++dy) {
        int iy = y + dy;
        if ((unsigned)iy >= HH) continue;
        #pragma unroll
        for (int dx = -1; dx <= 1; ++dx) {
            int ix = xx + dx;
            if ((unsigned)ix >= WW) continue;
            m = fmaxf(m, mask0[(b * HH + iy) * WW + ix]);
        }
    }
    mask1[t] = (m > 0.f) ? 1.f : 0.f;
}

// ---------- 2b: transpose-dilate mask: mask4[B][513][513] ----------
__global__ void k_mask4(const float* __restrict__ mask1, float* __restrict__ mask4, int total) {
    int t = blockIdx.x * blockDim.x + threadIdx.x;
    if (t >= total) return;
    int ox = t % HT;
    int oy = (t / HT) % HT;
    int b  = t / (HT * HT);
    float m = 0.f;
    #pragma unroll
    for (int ky = 0; ky < 3; ++ky) {
        int q = oy + ky - 2;
        if ((q & 1) || (unsigned)(q >> 1) >= (unsigned)HH) continue;
        int iy = q >> 1;
        #pragma unroll
        for (int kx = 0; kx < 3; ++kx) {
            int r = ox + kx - 2;
            if ((r & 1) || (unsigned)(r >> 1) >= (unsigned)WW) continue;
            m = fmaxf(m, mask1[(b * HH + iy) * WW + (r >> 1)]);
        }
    }
    mask4[t] = (m > 0.f) ? 1.f : 0.f;
}

// ---------- 2c: cast x fp32 -> bf16 (8 elems/thread) ----------
__global__ void k_cast(const float* __restrict__ src, unsigned short* __restrict__ dst, int n8) {
    int i = blockIdx.x * blockDim.x + threadIdx.x;
    if (i >= n8) return;
    float4 a = ((const float4*)src)[2 * i];
    float4 c = ((const float4*)src)[2 * i + 1];
    uint4 o;
    o.x = (unsigned)f2bf(a.x) | ((unsigned)f2bf(a.y) << 16);
    o.y = (unsigned)f2bf(a.z) | ((unsigned)f2bf(a.w) << 16);
    o.z = (unsigned)f2bf(c.x) | ((unsigned)f2bf(c.y) << 16);
    o.w = (unsigned)f2bf(c.z) | ((unsigned)f2bf(c.w) << 16);
    ((uint4*)dst)[i] = o;
}

// ---------- 2d: pack weights [K][64] fp32 -> MFMA B-fragment order ----------
// dst[t][nb][lane][j] (bf16) = w[k][n], k = t*32 + (lane>>4)*8 + j, n = nb*16 + (lane&15)
__global__ void k_pack(const float* __restrict__ w, unsigned short* __restrict__ dst, int T) {
    int t = blockIdx.x * blockDim.x + threadIdx.x;
    if (t >= T * 256) return;
    int step = t >> 8;
    int r = t & 255;
    int nb = r >> 6;
    int l = r & 63;
    int k = step * 32 + ((l >> 4) * 8);
    int n = nb * 16 + (l & 15);
    unsigned short tmp[8];
    #pragma unroll
    for (int j = 0; j < 8; ++j) tmp[j] = f2bf(w[(size_t)(k + j) * 64 + n]);
    uint4 o;
    o.x = (unsigned)tmp[0] | ((unsigned)tmp[1] << 16);
    o.y = (unsigned)tmp[2] | ((unsigned)tmp[3] << 16);
    o.z = (unsigned)tmp[4] | ((unsigned)tmp[5] << 16);
    o.w = (unsigned)tmp[6] | ((unsigned)tmp[7] << 16);
    *(uint4*)(dst + (size_t)((step * 4 + nb) * 64 + l) * 8) = o;
}

// ---------- MFMA conv: wave = 64 px x 64 cout ----------
// B staged in LDS per-ky (A/B round 0 vs 1: LDS B wins). XCD-chunk swizzle
// (round 1: FETCH 200->71 MB). NEW: explicit register double-buffer of A so
// next-kx-phase loads issue during current phase's MFMAs; per-ky prologue A
// loads issue BEFORE the staging barrier (vmcnt(0) drain completes them free).
enum Mode { CONV, CONVT2 };

template <int CIN, int IN_H, int IN_W, int OUT_H, int OUT_W, int PAD,
          Mode MODE, bool MASKED, bool OUT_F32>
__global__ __launch_bounds__(256, 2) void k_conv_mfma(
    const unsigned short* __restrict__ in,   // bf16 [B][IN_H][IN_W][CIN]
    const unsigned short* __restrict__ bp,   // packed B frags [T][4][64][8], T=9*CIN/32
    const float* __restrict__ bias,          // [64]
    const float* __restrict__ mask,          // [B][OUT_H][OUT_W] (if MASKED)
    void* __restrict__ outv)                 // bf16 or fp32 [B][OUT_H][OUT_W][64]
{
    constexpr int H2 = CIN / 32;                 // K-steps per tap
    constexpr int XT = (OUT_W + 255) / 256;      // 256 px per block
    __shared__ __align__(16) unsigned short lb[3 * H2 * 2048];  // one ky-phase of B

    // --- XCD-aware bijective swizzle: each XCD gets a contiguous chunk ---
    int nwg  = (int)gridDim.x;
    int orig = (int)blockIdx.x;
    int q8 = nwg >> 3, r8 = nwg & 7;
    int xcd = orig & 7, pos = orig >> 3;
    int blk = (xcd < r8 ? xcd * (q8 + 1) : r8 * (q8 + 1) + (xcd - r8) * q8) + pos;

    int s = blk % XT;
    int y = (blk / XT) % OUT_H;
    int b = blk / (XT * OUT_H);
    int tid  = threadIdx.x;
    int lane = tid & 63;
    int wid  = tid >> 6;
    int m    = lane & 15;
    int quad = lane >> 4;

    int px_base, par;
    if constexpr (MODE == CONV) { px_base = s * 256 + wid * 64; par = 0; }
    else { par = wid & 1; px_base = s * 256 + (wid >> 1) * 128; }

    // kx-phase schedule (wave-uniform)
    int nkx, kx0, kxstep;
    if constexpr (MODE == CONV) { nkx = 3; kx0 = 0; kxstep = 1; }
    else { nkx = (par == 0) ? 2 : 1; kx0 = par; kxstep = 2; }

    f32x4 acc[4][4] = {};
    uint4 Abuf[2][H2][4];     // double-buffered A fragments
    bool  vbuf[2][4];         // validity per f for each buffer

    auto loadA = [&](int bufi, int kx, const unsigned short* inrow) {
        int ix[4];
        #pragma unroll
        for (int f = 0; f < 4; ++f) {
            int ox, t;
            if constexpr (MODE == CONV) {
                ox = px_base + f * 16 + m;
                t  = ox + kx - PAD;
            } else {
                ox = px_base + 2 * (f * 16 + m) + par;
                t  = (ox + kx - 2) >> 1;          // even numerator by parity
            }
            vbuf[bufi][f] = (ox < OUT_W) & ((unsigned)t < (unsigned)IN_W);
            ix[f] = min(max(t, 0), IN_W - 1);
        }
        #pragma unroll
        for (int half = 0; half < H2; ++half)
            #pragma unroll
            for (int f = 0; f < 4; ++f)
                Abuf[bufi][half][f] =
                    *(const uint4*)(inrow + (size_t)ix[f] * CIN + half * 32 + quad * 8);
    };

    auto doPhase = [&](int bufi, int kx) {
        #pragma unroll
        for (int half = 0; half < H2; ++half) {
            int tl = kx * H2 + half;
            const unsigned short* lbt = lb + tl * 2048 + lane * 8;
            bf16x8 bfr[4];
            #pragma unroll
            for (int nb = 0; nb < 4; ++nb)
                bfr[nb] = *(const bf16x8*)(lbt + nb * 512);
            #pragma unroll
            for (int f = 0; f < 4; ++f) {
                uint4 av = vbuf[bufi][f] ? Abuf[bufi][half][f]
                                         : make_uint4(0u, 0u, 0u, 0u);
                bf16x8 a = __builtin_bit_cast(bf16x8, av);
                #pragma unroll
                for (int nb = 0; nb < 4; ++nb)
                    acc[f][nb] = __builtin_amdgcn_mfma_f32_16x16x32_bf16(
                        a, bfr[nb], acc[f][nb], 0, 0, 0);
            }
        }
    };

    #pragma unroll
    for (int ky = 0; ky < 3; ++ky) {
        int iy; bool rowv;
        if constexpr (MODE == CONV) {
            iy = y + ky - PAD;
            rowv = (unsigned)iy < (unsigned)IN_H;
        } else {
            int q = y + ky - 2;
            rowv = (!(q & 1)) && ((unsigned)(q >> 1) < (unsigned)IN_H);
            iy = q >> 1;
        }
        if (!rowv) continue;                      // block-uniform (y, ky uniform)

        const unsigned short* inrow = in + (size_t)(b * IN_H + iy) * IN_W * CIN;

        // prologue A-prefetch for this ky: issued BEFORE the staging barrier,
        // so the barrier's vmcnt drain completes it with zero exposed latency.
        loadA(0, kx0, inrow);

        __syncthreads();
        {   // stage this ky's 3*H2 t-steps of packed B into LDS (12/24 KB)
            const uint4* src = (const uint4*)bp + (size_t)ky * 3 * H2 * 256;
            uint4* dst = (uint4*)lb;
            #pragma unroll
            for (int j = 0; j < 3 * H2; ++j)
                dst[j * 256 + tid] = src[j * 256 + tid];
        }
        __syncthreads();

        #pragma unroll
        for (int i = 0; i < 3; ++i) {
            if (i < nkx) {
                if (i + 1 < nkx)                  // prefetch next kx phase
                    loadA((i + 1) & 1, kx0 + (i + 1) * kxstep, inrow);
                doPhase(i & 1, kx0 + i * kxstep);
            }
        }
    }

    // epilogue: C/D layout col = lane&15 (cout in nb), row = quad*4+reg (pixel in frag)
    int n0 = m;
    float bv[4];
    #pragma unroll
    for (int nb = 0; nb < 4; ++nb) bv[nb] = bias[nb * 16 + n0];
    #pragma unroll
    for (int f = 0; f < 4; ++f) {
        #pragma unroll
        for (int reg = 0; reg < 4; ++reg) {
            int i = f * 16 + quad * 4 + reg;
            int pm;
            if constexpr (MODE == CONV) pm = px_base + i;
            else pm = px_base + 2 * i + par;
            if (pm >= OUT_W) continue;
            size_t pix = (size_t)(b * OUT_H + y) * OUT_W + pm;
            float mk = 1.f;
            if constexpr (MASKED) mk = mask[pix];
            #pragma unroll
            for (int nb = 0; nb < 4; ++nb) {
                float o = fmaxf((acc[f][nb][reg] + bv[nb]) * mk, 0.f);
                if constexpr (OUT_F32)
                    ((float*)outv)[pix * 64 + nb * 16 + n0] = o;
                else
                    ((unsigned short*)outv)[pix * 64 + nb * 16 + n0] = f2bf(o);
            }
        }
    }
}

// ---------- host ----------
extern "C" void kernel_launch(void* const* d_in, const int* in_sizes, int n_in,
                              void* d_out, int out_size, void* d_ws, size_t ws_size,
                              hipStream_t stream) {
    const float* feat = (const float*)d_in[0];
    const int* coors  = (const int*)d_in[1];
    const float* w1 = (const float*)d_in[3];
    const float* b1 = (const float*)d_in[4];
    const float* w2 = (const float*)d_in[5];
    const float* b2 = (const float*)d_in[6];
    const float* w3 = (const float*)d_in[7];
    const float* b3 = (const float*)d_in[8];
    const float* wt = (const float*)d_in[9];
    const float* bt = (const float*)d_in[10];
    const float* w5 = (const float*)d_in[11];
    const float* b5 = (const float*)d_in[12];

    int N = in_sizes[0] / 32;  // 200000

    const size_t MB = 1024 * 1024;
    char* ws = (char*)d_ws;
    // layout (liveness-based reuse), total 177 MB:
    unsigned short* pk1 = (unsigned short*)(ws);             // 36,864 B
    unsigned short* pk2 = (unsigned short*)(ws + 36864);     // 73,728 B
    unsigned short* pk3 = (unsigned short*)(ws + 110592);
    unsigned short* pkt = (unsigned short*)(ws + 184320);
    unsigned short* pk5 = (unsigned short*)(ws + 258048);    // ends 331,776
    float* mask1 = (float*)(ws + 1 * MB);                    // 1 MB
    float* mask4 = (float*)(ws + 2 * MB);                    // 4.02 MB
    float* mask0 = (float*)(ws + 7 * MB);                    // 1 MB   (contiguous with x)
    float* x_f32 = (float*)(ws + 8 * MB);                    // 33.55 MB
    unsigned short* x_bf  = (unsigned short*)(ws + 42 * MB); // 16.78 MB
    unsigned short* h1    = (unsigned short*)(ws + 59 * MB); // 33.55 MB
    unsigned short* h2    = (unsigned short*)(ws + 93 * MB); // 33.55 MB
    unsigned short* h3    = (unsigned short*)(ws + 8 * MB);  // reuses x_f32 (dead after cast)
    unsigned short* h4    = (unsigned short*)(ws + 42 * MB); // 134.75 MB, reuses x_bf/h1/h2

    // 0: zero mask0 + x (contiguous 34,603,008 B)
    int nz4 = (262144 + 8388608) / 4;
    k_zero<<<(nz4 + 255) / 256, 256, 0, stream>>>(mask0, nz4);

    // 1: scatter (fp32 atomics)
    k_scatter<<<(N * 32 + 255) / 256, 256, 0, stream>>>(feat, coors, x_f32, mask0, N);

    // 2: masks + cast + weight packing
    k_mask1<<<(BATCH * HH * WW) / 256, 256, 0, stream>>>(mask0, mask1, BATCH * HH * WW);
    int m4tot = BATCH * HT * HT;
    k_mask4<<<(m4tot + 255) / 256, 256, 0, stream>>>(mask1, mask4, m4tot);
    k_cast<<<(1048576 + 255) / 256, 256, 0, stream>>>(x_f32, x_bf, 1048576);
    k_pack<<<9, 256, 0, stream>>>(w1, pk1, 9);
    k_pack<<<18, 256, 0, stream>>>(w2, pk2, 18);
    k_pack<<<18, 256, 0, stream>>>(w3, pk3, 18);
    k_pack<<<18, 256, 0, stream>>>(wt, pkt, 18);
    k_pack<<<18, 256, 0, stream>>>(w5, pk5, 18);

    // 3-5: conv stack at 256x256 (bf16 MFMA, 256 px/block)
    k_conv_mfma<32, 256, 256, 256, 256, 1, CONV, true, false>
        <<<BATCH * HH * 1, 256, 0, stream>>>(x_bf, pk1, b1, mask1, h1);
    k_conv_mfma<64, 256, 256, 256, 256, 1, CONV, true, false>
        <<<BATCH * HH * 1, 256, 0, stream>>>(h1, pk2, b2, mask1, h2);
    k_conv_mfma<64, 256, 256, 256, 256, 1, CONV, true, false>
        <<<BATCH * HH * 1, 256, 0, stream>>>(h2, pk3, b3, mask1, h3);

    // 6: transpose conv 256 -> 513 (parity-specialized waves)
    k_conv_mfma<64, 256, 256, HT, HT, 0, CONVT2, true, false>
        <<<BATCH * HT * 3, 256, 0, stream>>>(h3, pkt, bt, mask4, h4);

    // 7: final VALID conv 513 -> 511 into d_out (fp32)
    k_conv_mfma<64, HT, HT, HO, HO, 0, CONV, false, true>
        <<<BATCH * HO * 2, 256, 0, stream>>>(h4, pk5, b5, nullptr, (float*)d_out);
}

// Round 3
// 551.159 us; speedup vs baseline: 1.4502x; 1.2971x over previous
//
#include <hip/hip_runtime.h>

#define BATCH 4
#define HH 256
#define WW 256
#define HT 513   // convT output spatial
#define HO 511   // final output spatial

typedef __attribute__((ext_vector_type(8))) short bf16x8;
typedef __attribute__((ext_vector_type(4))) float f32x4;

// ---------- bf16 helpers ----------
__device__ __forceinline__ unsigned short f2bf(float f) {
    unsigned b = __float_as_uint(f);
    unsigned r = (b + 0x7fffu + ((b >> 16) & 1u)) >> 16;  // RNE
    return (unsigned short)r;
}

// async global->LDS, 16B per lane. LDS dest must be wave-uniform base (+lane*16).
typedef __attribute__((address_space(3))) unsigned int lds_u32;
typedef const __attribute__((address_space(1))) unsigned int g_u32;
__device__ __forceinline__ void gload16(const void* g, void* l) {
    __builtin_amdgcn_global_load_lds((g_u32*)g, (lds_u32*)l, 16, 0, 0);
}

// ---------- 0: zero a float4 region ----------
__global__ void k_zero(float* __restrict__ p, int n4) {
    int i = blockIdx.x * blockDim.x + threadIdx.x;
    if (i < n4) ((float4*)p)[i] = make_float4(0.f, 0.f, 0.f, 0.f);
}

// ---------- 1: scatter-add features (fp32), set occupancy ----------
__global__ void k_scatter(const float* __restrict__ feat,
                          const int* __restrict__ coors,
                          float* __restrict__ x, float* __restrict__ mask0, int N) {
    int t = blockIdx.x * blockDim.x + threadIdx.x;
    int n = t >> 5, c = t & 31;
    if (n >= N) return;
    int b  = coors[n * 3 + 0];
    int y  = coors[n * 3 + 1];
    int xx = coors[n * 3 + 2];
    float f = feat[n * 32 + c];
    int pix = (b * HH + y) * WW + xx;
    atomicAdd(&x[pix * 32 + c], f);
    if (c == 0) mask0[pix] = 1.0f;
}

// ---------- 2: 3x3 dilate mask (SAME) ----------
__global__ void k_mask1(const float* __restrict__ mask0, float* __restrict__ mask1, int total) {
    int t = blockIdx.x * blockDim.x + threadIdx.x;
    if (t >= total) return;
    int xx = t % WW;
    int y  = (t / WW) % HH;
    int b  = t / (WW * HH);
    float m = 0.f;
    #pragma unroll
    for (int dy = -1; dy <= 1; ++dy) {
        int iy = y + dy;
        if ((unsigned)iy >= HH) continue;
        #pragma unroll
        for (int dx = -1; dx <= 1; ++dx) {
            int ix = xx + dx;
            if ((unsigned)ix >= WW) continue;
            m = fmaxf(m, mask0[(b * HH + iy) * WW + ix]);
        }
    }
    mask1[t] = (m > 0.f) ? 1.f : 0.f;
}

// ---------- 2b: transpose-dilate mask: mask4[B][513][513] ----------
__global__ void k_mask4(const float* __restrict__ mask1, float* __restrict__ mask4, int total) {
    int t = blockIdx.x * blockDim.x + threadIdx.x;
    if (t >= total) return;
    int ox = t % HT;
    int oy = (t / HT) % HT;
    int b  = t / (HT * HT);
    float m = 0.f;
    #pragma unroll
    for (int ky = 0; ky < 3; ++ky) {
        int q = oy + ky - 2;
        if ((q & 1) || (unsigned)(q >> 1) >= (unsigned)HH) continue;
        int iy = q >> 1;
        #pragma unroll
        for (int kx = 0; kx < 3; ++kx) {
            int r = ox + kx - 2;
            if ((r & 1) || (unsigned)(r >> 1) >= (unsigned)WW) continue;
            m = fmaxf(m, mask1[(b * HH + iy) * WW + (r >> 1)]);
        }
    }
    mask4[t] = (m > 0.f) ? 1.f : 0.f;
}

// ---------- 2c: cast x fp32 -> bf16 (8 elems/thread) ----------
__global__ void k_cast(const float* __restrict__ src, unsigned short* __restrict__ dst, int n8) {
    int i = blockIdx.x * blockDim.x + threadIdx.x;
    if (i >= n8) return;
    float4 a = ((const float4*)src)[2 * i];
    float4 c = ((const float4*)src)[2 * i + 1];
    uint4 o;
    o.x = (unsigned)f2bf(a.x) | ((unsigned)f2bf(a.y) << 16);
    o.y = (unsigned)f2bf(a.z) | ((unsigned)f2bf(a.w) << 16);
    o.z = (unsigned)f2bf(c.x) | ((unsigned)f2bf(c.y) << 16);
    o.w = (unsigned)f2bf(c.z) | ((unsigned)f2bf(c.w) << 16);
    ((uint4*)dst)[i] = o;
}

// ---------- 2d: pack weights [K][64] fp32 -> MFMA B-fragment order ----------
// dst[t][nb][lane][j] (bf16) = w[k][n], k = t*32 + (lane>>4)*8 + j, n = nb*16 + (lane&15)
__global__ void k_pack(const float* __restrict__ w, unsigned short* __restrict__ dst, int T) {
    int t = blockIdx.x * blockDim.x + threadIdx.x;
    if (t >= T * 256) return;
    int step = t >> 8;
    int r = t & 255;
    int nb = r >> 6;
    int l = r & 63;
    int k = step * 32 + ((l >> 4) * 8);
    int n = nb * 16 + (l & 15);
    unsigned short tmp[8];
    #pragma unroll
    for (int j = 0; j < 8; ++j) tmp[j] = f2bf(w[(size_t)(k + j) * 64 + n]);
    uint4 o;
    o.x = (unsigned)tmp[0] | ((unsigned)tmp[1] << 16);
    o.y = (unsigned)tmp[2] | ((unsigned)tmp[3] << 16);
    o.z = (unsigned)tmp[4] | ((unsigned)tmp[5] << 16);
    o.w = (unsigned)tmp[6] | ((unsigned)tmp[7] << 16);
    *(uint4*)(dst + (size_t)((step * 4 + nb) * 64 + l) * 8) = o;
}

// ---------- MFMA conv: wave = 64 px x 64 cout ----------
// m97 structure: input ROW staged in LDS once per ky via global_load_lds
// (XOR-swizzled via pre-swizzled global source, rule #21), B tile also
// global_load_lds. Inner loop = pure ds_read_b128 + MFMA. OOB pixels point
// at a zero page during staging -> no per-K-step validity cndmask.
enum Mode { CONV, CONVT2 };

template <int CIN, int IN_H, int IN_W, int OUT_H, int OUT_W, int PAD,
          Mode MODE, bool MASKED, bool OUT_F32>
__global__ __launch_bounds__(256, 2) void k_conv_mfma(
    const unsigned short* __restrict__ in,   // bf16 [B][IN_H][IN_W][CIN]
    const unsigned short* __restrict__ bp,   // packed B frags [T][4][64][8], T=9*CIN/32
    const float* __restrict__ bias,          // [64]
    const float* __restrict__ mask,          // [B][OUT_H][OUT_W] (if MASKED)
    const unsigned short* __restrict__ zpg,  // >=16B of zeros (halo source)
    void* __restrict__ outv)                 // bf16 or fp32 [B][OUT_H][OUT_W][64]
{
    constexpr int H2  = CIN / 32;                 // K-steps per tap
    constexpr int XT  = (OUT_W + 255) / 256;      // 256 px per block
    constexpr int CPX = CIN / 8;                  // 16B chunks per pixel (8 or 4)
    constexpr int CSH = (CIN == 64) ? 3 : 2;      // log2(CPX)
    // staged pixels per ky; chosen so APX*CPX % 256 == 0 (exact gload iters)
    constexpr int APX = (MODE == CONV) ? ((CIN == 32) ? 320 : 288) : 160;
    constexpr int NITER = APX * CPX / 256;
    constexpr int BBYTES = 3 * H2 * 4096;         // B tile bytes for one ky

    __shared__ __align__(16) char lds[BBYTES + APX * CIN * 2];

    // --- XCD-aware bijective swizzle: each XCD gets a contiguous chunk ---
    int nwg  = (int)gridDim.x;
    int orig = (int)blockIdx.x;
    int q8 = nwg >> 3, r8 = nwg & 7;
    int xcd = orig & 7, pos = orig >> 3;
    int blk = (xcd < r8 ? xcd * (q8 + 1) : r8 * (q8 + 1) + (xcd - r8) * q8) + pos;

    int s = blk % XT;
    int y = (blk / XT) % OUT_H;
    int b = blk / (XT * OUT_H);
    int tid  = threadIdx.x;
    int lane = tid & 63;
    int wid  = tid >> 6;
    int m    = lane & 15;
    int quad = lane >> 4;

    int px_base, par;
    if constexpr (MODE == CONV) { px_base = s * 256 + wid * 64; par = 0; }
    else { par = wid & 1; px_base = s * 256 + (wid >> 1) * 128; }

    // kx-phase schedule (wave-uniform)
    int nkx, kx0, kxstep;
    if constexpr (MODE == CONV) { nkx = 3; kx0 = 0; kxstep = 1; }
    else { nkx = (par == 0) ? 2 : 1; kx0 = par; kxstep = 2; }

    // first staged input pixel (global index) for this block
    int t0;
    if constexpr (MODE == CONV) t0 = s * 256 - PAD;
    else                        t0 = s * 128 - 1;

    // wave's base local pixel for fragment reads (add f*16 + kx-offset later)
    int pb;
    if constexpr (MODE == CONV) pb = wid * 64 + m;
    else                        pb = (wid >> 1) * 64 + m;

    const unsigned short* lA = (const unsigned short*)(lds + BBYTES);
    const unsigned short* lB = (const unsigned short*)lds;

    f32x4 acc[4][4] = {};

    #pragma unroll
    for (int ky = 0; ky < 3; ++ky) {
        int iy; bool rowv;
        if constexpr (MODE == CONV) {
            iy = y + ky - PAD;
            rowv = (unsigned)iy < (unsigned)IN_H;
        } else {
            int q = y + ky - 2;
            rowv = (!(q & 1)) && ((unsigned)(q >> 1) < (unsigned)IN_H);
            iy = q >> 1;
        }
        if (!rowv) continue;                      // block-uniform (y, ky uniform)

        const unsigned short* inrow = in + (size_t)(b * IN_H + iy) * IN_W * CIN;

        __syncthreads();   // previous ky's ds_reads done before overwrite

        // stage B tile for this ky (linear, conflict-free reads)
        {
            const uint4* bsrc = (const uint4*)bp + (size_t)ky * 3 * H2 * 256;
            #pragma unroll
            for (int j = 0; j < 3 * H2; ++j)
                gload16(bsrc + j * 256 + tid,
                        lds + (size_t)(j * 256 + (tid & ~63)) * 16);
        }
        // stage A row, XOR-swizzled via pre-swizzled global source.
        // LDS chunk ci holds global chunk (p*CPX + (c' ^ swz(p))), p=ci>>CSH.
        #pragma unroll
        for (int j = 0; j < NITER; ++j) {
            int ci = j * 256 + tid;
            int p  = ci >> CSH;
            int cc = ci & (CPX - 1);
            int swz = (CIN == 64) ? (p & 7) : ((p >> 1) & 3);
            int c  = cc ^ swz;
            int t  = t0 + p;
            const unsigned short* g =
                ((unsigned)t < (unsigned)IN_W) ? inrow + (size_t)t * CIN + c * 8 : zpg;
            gload16(g, lds + BBYTES + (size_t)(j * 256 + (tid & ~63)) * 16);
        }
        __syncthreads();   // vmcnt(0) drain: staged data visible

        #pragma unroll
        for (int i = 0; i < 3; ++i) {
            if (i < nkx) {
                int kx = kx0 + i * kxstep;
                int kxo;
                if constexpr (MODE == CONV) kxo = kx;
                else kxo = ((par + kx - 2) >> 1) + 1;
                #pragma unroll
                for (int half = 0; half < H2; ++half) {
                    int tl = kx * H2 + half;
                    const unsigned short* lbt = lB + tl * 2048 + lane * 8;
                    bf16x8 bfr[4];
                    #pragma unroll
                    for (int nb = 0; nb < 4; ++nb)
                        bfr[nb] = *(const bf16x8*)(lbt + nb * 512);
                    #pragma unroll
                    for (int f = 0; f < 4; ++f) {
                        int p = pb + f * 16 + kxo;
                        int swz = (CIN == 64) ? (p & 7) : ((p >> 1) & 3);
                        int c = ((CIN == 64) ? (half * 4 + quad) : quad) ^ swz;
                        bf16x8 a = *(const bf16x8*)(lA + (size_t)p * CIN + c * 8);
                        #pragma unroll
                        for (int nb = 0; nb < 4; ++nb)
                            acc[f][nb] = __builtin_amdgcn_mfma_f32_16x16x32_bf16(
                                a, bfr[nb], acc[f][nb], 0, 0, 0);
                    }
                }
            }
        }
    }

    // epilogue: C/D layout col = lane&15 (cout in nb), row = quad*4+reg (pixel in frag)
    int n0 = m;
    float bv[4];
    #pragma unroll
    for (int nb = 0; nb < 4; ++nb) bv[nb] = bias[nb * 16 + n0];
    #pragma unroll
    for (int f = 0; f < 4; ++f) {
        #pragma unroll
        for (int reg = 0; reg < 4; ++reg) {
            int i = f * 16 + quad * 4 + reg;
            int pm;
            if constexpr (MODE == CONV) pm = px_base + i;
            else pm = px_base + 2 * i + par;
            if (pm >= OUT_W) continue;
            size_t pix = (size_t)(b * OUT_H + y) * OUT_W + pm;
            float mk = 1.f;
            if constexpr (MASKED) mk = mask[pix];
            #pragma unroll
            for (int nb = 0; nb < 4; ++nb) {
                float o = fmaxf((acc[f][nb][reg] + bv[nb]) * mk, 0.f);
                if constexpr (OUT_F32)
                    ((float*)outv)[pix * 64 + nb * 16 + n0] = o;
                else
                    ((unsigned short*)outv)[pix * 64 + nb * 16 + n0] = f2bf(o);
            }
        }
    }
}

// ---------- host ----------
extern "C" void kernel_launch(void* const* d_in, const int* in_sizes, int n_in,
                              void* d_out, int out_size, void* d_ws, size_t ws_size,
                              hipStream_t stream) {
    const float* feat = (const float*)d_in[0];
    const int* coors  = (const int*)d_in[1];
    const float* w1 = (const float*)d_in[3];
    const float* b1 = (const float*)d_in[4];
    const float* w2 = (const float*)d_in[5];
    const float* b2 = (const float*)d_in[6];
    const float* w3 = (const float*)d_in[7];
    const float* b3 = (const float*)d_in[8];
    const float* wt = (const float*)d_in[9];
    const float* bt = (const float*)d_in[10];
    const float* w5 = (const float*)d_in[11];
    const float* b5 = (const float*)d_in[12];

    int N = in_sizes[0] / 32;  // 200000

    const size_t MB = 1024 * 1024;
    char* ws = (char*)d_ws;
    // layout (liveness-based reuse), total 177 MB:
    unsigned short* pk1 = (unsigned short*)(ws);             // 36,864 B
    unsigned short* pk2 = (unsigned short*)(ws + 36864);     // 73,728 B
    unsigned short* pk3 = (unsigned short*)(ws + 110592);
    unsigned short* pkt = (unsigned short*)(ws + 184320);
    unsigned short* pk5 = (unsigned short*)(ws + 258048);    // ends 331,776
    unsigned short* zpg = (unsigned short*)(ws + 960 * 1024); // 256 B zero page
    float* mask1 = (float*)(ws + 1 * MB);                    // 1 MB
    float* mask4 = (float*)(ws + 2 * MB);                    // 4.02 MB
    float* mask0 = (float*)(ws + 7 * MB);                    // 1 MB   (contiguous with x)
    float* x_f32 = (float*)(ws + 8 * MB);                    // 33.55 MB
    unsigned short* x_bf  = (unsigned short*)(ws + 42 * MB); // 16.78 MB
    unsigned short* h1    = (unsigned short*)(ws + 59 * MB); // 33.55 MB
    unsigned short* h2    = (unsigned short*)(ws + 93 * MB); // 33.55 MB
    unsigned short* h3    = (unsigned short*)(ws + 8 * MB);  // reuses x_f32 (dead after cast)
    unsigned short* h4    = (unsigned short*)(ws + 42 * MB); // 134.75 MB, reuses x_bf/h1/h2

    // 0: zero mask0 + x (contiguous 34,603,008 B) and the zero page
    int nz4 = (262144 + 8388608) / 4;
    k_zero<<<(nz4 + 255) / 256, 256, 0, stream>>>(mask0, nz4);
    k_zero<<<1, 16, 0, stream>>>((float*)zpg, 16);

    // 1: scatter (fp32 atomics)
    k_scatter<<<(N * 32 + 255) / 256, 256, 0, stream>>>(feat, coors, x_f32, mask0, N);

    // 2: masks + cast + weight packing
    k_mask1<<<(BATCH * HH * WW) / 256, 256, 0, stream>>>(mask0, mask1, BATCH * HH * WW);
    int m4tot = BATCH * HT * HT;
    k_mask4<<<(m4tot + 255) / 256, 256, 0, stream>>>(mask1, mask4, m4tot);
    k_cast<<<(1048576 + 255) / 256, 256, 0, stream>>>(x_f32, x_bf, 1048576);
    k_pack<<<9, 256, 0, stream>>>(w1, pk1, 9);
    k_pack<<<18, 256, 0, stream>>>(w2, pk2, 18);
    k_pack<<<18, 256, 0, stream>>>(w3, pk3, 18);
    k_pack<<<18, 256, 0, stream>>>(wt, pkt, 18);
    k_pack<<<18, 256, 0, stream>>>(w5, pk5, 18);

    // 3-5: conv stack at 256x256 (bf16 MFMA, 256 px/block)
    k_conv_mfma<32, 256, 256, 256, 256, 1, CONV, true, false>
        <<<BATCH * HH * 1, 256, 0, stream>>>(x_bf, pk1, b1, mask1, zpg, h1);
    k_conv_mfma<64, 256, 256, 256, 256, 1, CONV, true, false>
        <<<BATCH * HH * 1, 256, 0, stream>>>(h1, pk2, b2, mask1, zpg, h2);
    k_conv_mfma<64, 256, 256, 256, 256, 1, CONV, true, false>
        <<<BATCH * HH * 1, 256, 0, stream>>>(h2, pk3, b3, mask1, zpg, h3);

    // 6: transpose conv 256 -> 513 (parity-specialized waves)
    k_conv_mfma<64, 256, 256, HT, HT, 0, CONVT2, true, false>
        <<<BATCH * HT * 3, 256, 0, stream>>>(h3, pkt, bt, mask4, zpg, h4);

    // 7: final VALID conv 513 -> 511 into d_out (fp32)
    k_conv_mfma<64, HT, HT, HO, HO, 0, CONV, false, true>
        <<<BATCH * HO * 2, 256, 0, stream>>>(h4, pk5, b5, nullptr, zpg, (float*)d_out);
}